// Round 7
// baseline (117.585 us; speedup 1.0000x reference)
//
#include <hip/hip_runtime.h>
#include <hip/hip_bf16.h>

#define BATCH 16384
#define DIM   512
#define UNITS 1024
// GAMMA = 0.5 folded into epilogue: out = exp(cross - 0.5*xsq - 0.5*musq)

typedef float v16f __attribute__((ext_vector_type(16)));

#define APITCH 516   // floats; %32==4 -> b128 phase reads near the structural floor
#define BPITCH 33

// Fragment-order prep.
// A8f layout: byte ((chunk*32 + kw)*64 + lane)*8, chunk=row/32, kw=k/16.
//   Lane l holds A[chunk*32 + (l&31)][kw*16 + (l>>5)*8 + 0..7] as fp8 e4m3.
// B8f layout: byte ((ng*32 + kw)*64 + lane)*8, ng = n/32.
//   Lane l holds B[kw*16 + (l>>5)*8 + 0..7][ng*32 + (l&31)].
// => every GEMM operand load is base + lane*8: fully coalesced 512 B.
// xsq/musq computed on ORIGINAL fp32 values. B blocks dispatched FIRST
// (latency-bound strided mu reads overlap the A-stream).
__global__ __launch_bounds__(256)
void prep_kernel(const float* __restrict__ in, const float* __restrict__ mu,
                 unsigned char* __restrict__ A8f, unsigned char* __restrict__ B8f,
                 float* __restrict__ xsq, float* __restrict__ musq) {
    __shared__ __attribute__((aligned(16))) char smem[512 * BPITCH * 4 + 1024];
    const int t  = threadIdx.x;
    const int l  = t & 63, w = t >> 6;
    const int ln = l & 31, h = l >> 5;

    if (blockIdx.x >= UNITS / 32) {
        // ---- A path: one block per 32-row chunk ----
        float* lds = (float*)smem;                       // [32][APITCH]
        float* red = (float*)(smem + 32 * APITCH * 4);   // [32][8]
        const int c = blockIdx.x - UNITS / 32;
        const float4* src = (const float4*)(in + (size_t)c * 32 * DIM);
        float4* l4 = (float4*)lds;
#pragma unroll
        for (int i = 0; i < 16; i++) {
            const int f = i * 256 + t;                   // float4 id 0..4095
            l4[(f >> 7) * (APITCH / 4) + (f & 127)] = src[f];
        }
        __syncthreads();
        float s = 0.f;
#pragma unroll
        for (int j = 0; j < 8; j++) {
            const int kw = w * 8 + j;
            const float* p = lds + ln * APITCH + kw * 16 + h * 8;
            float4 f0 = *(const float4*)p;
            float4 f1 = *(const float4*)(p + 4);
            s += f0.x * f0.x + f0.y * f0.y + f0.z * f0.z + f0.w * f0.w
               + f1.x * f1.x + f1.y * f1.y + f1.z * f1.z + f1.w * f1.w;
            int lo = __builtin_amdgcn_cvt_pk_fp8_f32(f0.x, f0.y, 0, false);
            lo     = __builtin_amdgcn_cvt_pk_fp8_f32(f0.z, f0.w, lo, true);
            int hi = __builtin_amdgcn_cvt_pk_fp8_f32(f1.x, f1.y, 0, false);
            hi     = __builtin_amdgcn_cvt_pk_fp8_f32(f1.z, f1.w, hi, true);
            *(int2*)(A8f + (((size_t)c * 32 + kw) * 64 + l) * 8) = make_int2(lo, hi);
        }
        red[ln * 8 + w * 2 + h] = s;   // each (row, col-range) summed exactly once
        __syncthreads();
        if (t < 32) {
            float a = 0.f;
#pragma unroll
            for (int i = 0; i < 8; i++) a += red[t * 8 + i];
            xsq[c * 32 + t] = a;
        }
    } else {
        // ---- B path: one block per 32-column group ----
        float* lds = (float*)smem;                       // [512][BPITCH]
        float* red = (float*)(smem + 512 * BPITCH * 4);  // [32][8]
        const int nb = blockIdx.x;
        const int n0 = nb * 32;
        const int col = t & 31, kg = t >> 5;
        float s = 0.f;
        for (int i = 0; i < 64; i++) {
            const int k = i * 8 + kg;
            float v = mu[(size_t)k * UNITS + n0 + col];
            s += v * v;
            lds[k * BPITCH + col] = v;
        }
        red[col * 8 + kg] = s;
        __syncthreads();
        if (t < 32) {
            float a = 0.f;
#pragma unroll
            for (int i = 0; i < 8; i++) a += red[t * 8 + i];
            musq[n0 + t] = a;
        }
#pragma unroll
        for (int j = 0; j < 8; j++) {
            const int kw = w * 8 + j;
            const float* p = lds + (kw * 16 + h * 8) * BPITCH + ln;
            float f[8];
#pragma unroll
            for (int i = 0; i < 8; i++) f[i] = p[i * BPITCH];
            int lo = __builtin_amdgcn_cvt_pk_fp8_f32(f[0], f[1], 0, false);
            lo     = __builtin_amdgcn_cvt_pk_fp8_f32(f[2], f[3], lo, true);
            int hi = __builtin_amdgcn_cvt_pk_fp8_f32(f[4], f[5], 0, false);
            hi     = __builtin_amdgcn_cvt_pk_fp8_f32(f[6], f[7], hi, true);
            *(int2*)(B8f + (((size_t)nb * 32 + kw) * 64 + l) * 8) = make_int2(lo, hi);
        }
    }
}

// Barrier-free, LDS-free RBF GEMM on fragment-order fp8.
// 1024 blocks x 4 waves, ALL resident (4 blocks/CU at VGPR<=128 -> 16
// waves/CU, single dispatch round). Wave tile 64x64: 2 A-chunks x 2 B-groups,
// 4 acc (64 VGPR), per kw: 2 A + 2 B loads feed 4 MFMAs (1.0 load/MFMA).
// Every VMEM op is lane-linear coalesced (512 B/inst). No __syncthreads,
// no LDS -> no vmcnt(0) drains; 4 waves/SIMD cover L2 latency.
// XCD swizzle: XCD b&7 owns a 2048-row, 1 MB L2-resident A slice.
__global__ __launch_bounds__(256, 4)
void rbf_gemm_kernel(const unsigned char* __restrict__ A8f,
                     const unsigned char* __restrict__ B8f,
                     const float* __restrict__ xsq,
                     const float* __restrict__ musq,
                     float* __restrict__ out) {
    const int t  = threadIdx.x;
    const int l  = t & 63;
    const int w  = t >> 6;
    const int ln = l & 31;
    const int h  = l >> 5;

    const int b  = blockIdx.x;      // 1024
    const int x  = b & 7;           // XCD (round-robin dispatch)
    const int q  = b >> 3;
    const int rg = q & 15;          // row-tile (128) within XCD slice
    const int cg = q >> 4;          // col-tile (128), 0..7
    const int m0 = x * 2048 + rg * 128 + (w >> 1) * 64;  // wave M origin
    const int n0 = cg * 128 + (w & 1) * 64;              // wave N origin

    // chunk stride = 32 kw * 64 lanes = 2048 longs
    const long* Af = (const long*)A8f + (size_t)(m0 >> 5) * 2048 + l;
    const long* Bf = (const long*)B8f + (size_t)(n0 >> 5) * 2048 + l;

    v16f acc[2][2];
#pragma unroll
    for (int c = 0; c < 2; c++)
#pragma unroll
        for (int j = 0; j < 2; j++) acc[c][j] = (v16f)0.f;

#pragma unroll 4
    for (int kw = 0; kw < 32; kw++) {
        long a0 = Af[kw * 64];
        long a1 = Af[2048 + kw * 64];
        long b0 = Bf[kw * 64];
        long b1 = Bf[2048 + kw * 64];
        acc[0][0] = __builtin_amdgcn_mfma_f32_32x32x16_fp8_fp8(a0, b0, acc[0][0], 0, 0, 0);
        acc[0][1] = __builtin_amdgcn_mfma_f32_32x32x16_fp8_fp8(a0, b1, acc[0][1], 0, 0, 0);
        acc[1][0] = __builtin_amdgcn_mfma_f32_32x32x16_fp8_fp8(a1, b0, acc[1][0], 0, 0, 0);
        acc[1][1] = __builtin_amdgcn_mfma_f32_32x32x16_fp8_fp8(a1, b1, acc[1][1], 0, 0, 0);
    }

    // Epilogue. C/D layout (m74/m101, dtype-indep): col = l&31,
    // row = (reg&3) + 8*(reg>>2) + 4*(l>>5). xsq via one coalesced load +
    // shuffle instead of 64 broadcast loads.
#pragma unroll
    for (int c = 0; c < 2; c++) {
        const int mc = m0 + c * 32;
        const float xv = -0.5f * xsq[mc + ln];   // lanes ln / ln+32 duplicate
#pragma unroll
        for (int j = 0; j < 2; j++) {
            const int nc = n0 + j * 32;
            const float mb = -0.5f * musq[nc + ln];
#pragma unroll
            for (int r = 0; r < 16; r++) {
                const int rl = (r & 3) + 8 * (r >> 2) + 4 * h;
                const float xb = __shfl(xv, rl, 64);   // lane rl holds row mc+rl
                float v = __expf(acc[c][j][r] + xb + mb);
                __builtin_nontemporal_store(
                    v, out + (size_t)(mc + rl) * UNITS + nc + ln);
            }
        }
    }
}

extern "C" void kernel_launch(void* const* d_in, const int* in_sizes, int n_in,
                              void* d_out, int out_size, void* d_ws, size_t ws_size,
                              hipStream_t stream) {
    const float* inputs = (const float*)d_in[0];   // [16384, 512] fp32
    const float* mu     = (const float*)d_in[1];   // [512, 1024] fp32
    float* out = (float*)d_out;                    // [16384, 1024] fp32

    char* ws = (char*)d_ws;
    unsigned char* A8f = (unsigned char*)ws;                           // 8 MiB
    unsigned char* B8f = (unsigned char*)(ws + (size_t)BATCH * DIM);   // 512 KiB
    float* xsq  = (float*)(ws + (size_t)BATCH * DIM + (size_t)UNITS * DIM);
    float* musq = xsq + BATCH;

    prep_kernel<<<UNITS / 32 + BATCH / 32, 256, 0, stream>>>(
        inputs, mu, A8f, B8f, xsq, musq);
    rbf_gemm_kernel<<<1024, 256, 0, stream>>>(A8f, B8f, xsq, musq, out);
}